// Round 17
// baseline (214.163 us; speedup 1.0000x reference)
//
#include <hip/hip_runtime.h>
#include <hip/hip_bf16.h>
#include <math.h>

#define B_ 2
#define S_ 2048
#define E_ 1024
#define H_ 16
#define D_ 64
#define M_ 4096   // B_*S_
#define NT2 32    // D_/2
#define KVB 64

typedef __bf16 bf16;
typedef __bf16 bf16x4 __attribute__((ext_vector_type(4)));
typedef __bf16 bf16x8 __attribute__((ext_vector_type(8)));
typedef float f32x4 __attribute__((ext_vector_type(4)));
typedef float f32x16 __attribute__((ext_vector_type(16)));

__device__ __forceinline__ void gload_lds16(const void* g, void* lds) {
  __builtin_amdgcn_global_load_lds(
      (const __attribute__((address_space(1))) unsigned int*)g,
      (__attribute__((address_space(3))) unsigned int*)lds, 16, 0, 0);
}

#define MFMA16(a, b, c) __builtin_amdgcn_mfma_f32_16x16x32_bf16(a, b, c, 0, 0, 0)
#define MFMA32(a, b, c) __builtin_amdgcn_mfma_f32_32x32x16_bf16(a, b, c, 0, 0, 0)

// ---------------- fused prep: split X + transpose/split 4 W + rope table ----
__global__ __launch_bounds__(256)
void prep_kernel(const float* __restrict__ x, const int* __restrict__ pos,
                 const float* __restrict__ Wq, const float* __restrict__ Wk,
                 const float* __restrict__ Wv, const float* __restrict__ Wo,
                 bf16* __restrict__ Xh, bf16* __restrict__ Xl,
                 bf16* __restrict__ Tqh, bf16* __restrict__ Tql,
                 bf16* __restrict__ Tkh, bf16* __restrict__ Tkl,
                 bf16* __restrict__ Tvh, bf16* __restrict__ Tvl,
                 bf16* __restrict__ Toh, bf16* __restrict__ Tol,
                 float* __restrict__ cosT, float* __restrict__ sinT) {
  const int bid = blockIdx.x;
  if (bid < 4096) {  // ---- split fp32 -> bf16 hi/lo (float4 per thread) ----
    int i = bid * 256 + threadIdx.x;
    float4 v = ((const float4*)x)[i];
    bf16 h0 = (bf16)v.x, h1 = (bf16)v.y, h2 = (bf16)v.z, h3 = (bf16)v.w;
    bf16x4 hv = {h0, h1, h2, h3};
    bf16x4 lv = {(bf16)(v.x - (float)h0), (bf16)(v.y - (float)h1),
                 (bf16)(v.z - (float)h2), (bf16)(v.w - (float)h3)};
    *(bf16x4*)(Xh + 4 * (size_t)i) = hv;
    *(bf16x4*)(Xl + 4 * (size_t)i) = lv;
  } else if (bid < 8192) {  // ---- transpose + split one 32x32 W tile ----
    int t = bid - 4096;
    int z = t >> 10, rem = t & 1023;
    int bx = rem & 31, by = rem >> 5;
    const float* W = z == 0 ? Wq : z == 1 ? Wk : z == 2 ? Wv : Wo;
    bf16* Th = z == 0 ? Tqh : z == 1 ? Tkh : z == 2 ? Tvh : Toh;
    bf16* Tl = z == 0 ? Tql : z == 1 ? Tkl : z == 2 ? Tvl : Tol;
    __shared__ float tile[32][33];
    const int tx = threadIdx.x & 31, ty = threadIdx.x >> 5;  // ty 0..7
    const int c0 = bx * 32, r0 = by * 32;
#pragma unroll
    for (int i = 0; i < 4; ++i)
      tile[ty + 8 * i][tx] = W[(size_t)(r0 + ty + 8 * i) * E_ + c0 + tx];
    __syncthreads();
#pragma unroll
    for (int i = 0; i < 4; ++i) {
      int rr = ty + 8 * i;
      float v = tile[tx][rr];  // = W[r0+tx][c0+rr]
      bf16 hv = (bf16)v;
      size_t oidx = (size_t)(c0 + rr) * E_ + r0 + tx;
      Th[oidx] = hv;
      Tl[oidx] = (bf16)(v - (float)hv);
    }
  } else {  // ---- RoPE cos/sin table ----
    int idx = (bid - 8192) * 256 + threadIdx.x;  // B_*S_*NT2
    int t = idx & 31, bs = idx >> 5;
    double th = pow(10000.0, -(double)(2 * t) / 64.0);
    float ang = (float)pos[bs] * (float)th;  // fp32 product (matches ref)
    double a = (double)ang;
    cosT[idx] = (float)cos(a);
    sinT[idx] = (float)sin(a);
  }
}

// ---------------- fused QKV split-bf16 GEMM, 128^2, 4 waves, BK=64 ---------
// r15's zero-conflict layout (merged 256B row [Ah 64k | Al 64k], swizzle
// slot ^= row&15 both-sides) with the wave grid reshaped 2Mx4N -> 2Mx2N:
// wave tile 64x32 -> 64x64 (2mi x 2ni frags), so per ks-step 8 ds_read_b128
// feed 12 MFMAs (0.67 reads/MFMA vs 1.0) — the r16 accounting showed LDS
// READ throughput is the binding resource (predicted MfmaUtil 32% = measured
// 31%), so cutting read/MFMA ratio 33% is the direct lever.  256 thr, LDS
// 64KB, 2 blocks/CU (8 waves/CU), grid 768 = 3 blocks/CU balanced.
// acc-split dropped (r12: neutral).
#define BMg 128
#define BNg 128
#define BKq 64

__global__ __launch_bounds__(256, 2)
void gemm_qkv_kernel(const bf16* __restrict__ Ah_g, const bf16* __restrict__ Al_g,
                     const bf16* __restrict__ BhQ, const bf16* __restrict__ BlQ,
                     const bf16* __restrict__ BhK, const bf16* __restrict__ BlK,
                     const bf16* __restrict__ BhV, const bf16* __restrict__ BlV,
                     const float* __restrict__ bqp, const float* __restrict__ bkp,
                     const float* __restrict__ bvp,
                     const float* __restrict__ cosT, const float* __restrict__ sinT,
                     bf16* __restrict__ Qh, bf16* __restrict__ Qlo,
                     bf16* __restrict__ Kh, bf16* __restrict__ Klo,
                     bf16* __restrict__ VTb) {
  __shared__ bf16 lA[BMg * 128];  // 32 KB: row = [Ah 64 bf16 | Al 64 bf16]
  __shared__ bf16 lB[BNg * 128];  // 32 KB
  const int tid = threadIdx.x;        // 0..255
  const int nb = blockIdx.x;          // 0..23
  const int third = nb >> 3;          // 0=Q 1=K 2=V
  const int n0 = (nb & 7) * BNg;
  const int m0 = blockIdx.y * BMg;
  const bf16* Bh_g = third == 0 ? BhQ : third == 1 ? BhK : BhV;
  const bf16* Bl_g = third == 0 ? BlQ : third == 1 ? BlK : BlV;
  const float* bias = third == 0 ? bqp : third == 1 ? bkp : bvp;
  const int wave = tid >> 6, lane = tid & 63;
  const int wr = wave >> 1, wc = wave & 1;  // 2M x 2N wave grid
  const int r = lane & 31, half = lane >> 5;
  const int KD = 1024;
  const int NK = KD / BKq;  // 16

  f32x16 acc[2][2] = {};  // [mi][ni]

  for (int kt = 0; kt < NK; ++kt) {
    const int k0 = kt * BKq;
    {
#pragma unroll
      for (int i = 0; i < 8; ++i) {
        int c = i * 256 + tid;          // 16B chunk 0..2047
        int row = c >> 4, u = c & 15;
        int us = u ^ (row & 15);        // pre-swizzled source slot
        int uu = us & 7;
        char* lpA = (char*)lA + (size_t)(i * 256 + wave * 64) * 16;
        char* lpB = (char*)lB + (size_t)(i * 256 + wave * 64) * 16;
        const bf16* sA = (us < 8) ? Ah_g : Al_g;
        const bf16* sB = (us < 8) ? Bh_g : Bl_g;
        gload_lds16((const char*)(sA + (size_t)(m0 + row) * KD + k0) + uu * 16,
                    lpA);
        gload_lds16((const char*)(sB + (size_t)(n0 + row) * KD + k0) + uu * 16,
                    lpB);
      }
    }
    __syncthreads();
#pragma unroll
    for (int ks = 0; ks < 4; ++ks) {
      bf16x8 a_h[2], a_l[2], b_h[2], b_l[2];
#pragma unroll
      for (int mi = 0; mi < 2; ++mi) {
        int row = wr * 64 + mi * 32 + r;
        int sw = (row & 15) << 4;
        const char* base = (const char*)lA + row * 256;
        a_h[mi] = *(const bf16x8*)(base + ((ks * 32 + half * 16) ^ sw));
        a_l[mi] = *(const bf16x8*)(base + ((128 + ks * 32 + half * 16) ^ sw));
      }
#pragma unroll
      for (int ni = 0; ni < 2; ++ni) {
        int row = wc * 64 + ni * 32 + r;
        int sw = (row & 15) << 4;
        const char* base = (const char*)lB + row * 256;
        b_h[ni] = *(const bf16x8*)(base + ((ks * 32 + half * 16) ^ sw));
        b_l[ni] = *(const bf16x8*)(base + ((128 + ks * 32 + half * 16) ^ sw));
      }
#pragma unroll
      for (int mi = 0; mi < 2; ++mi)
#pragma unroll
        for (int ni = 0; ni < 2; ++ni) {
          acc[mi][ni] = MFMA32(a_h[mi], b_h[ni], acc[mi][ni]);
          acc[mi][ni] = MFMA32(a_h[mi], b_l[ni], acc[mi][ni]);
          acc[mi][ni] = MFMA32(a_l[mi], b_h[ni], acc[mi][ni]);
        }
    }
    __syncthreads();
  }

  // ---- epilogue ----
#pragma unroll
  for (int mi = 0; mi < 2; ++mi)
#pragma unroll
    for (int ni = 0; ni < 2; ++ni) {
      const int gcol = n0 + wc * 64 + ni * 32 + r;
      const float bv = bias[gcol];
      if (third < 2) {  // Q or K: RoPE (+scale for Q), split
        bf16* outH = third == 0 ? Qh : Kh;
        bf16* outL = third == 0 ? Qlo : Klo;
        const int h = gcol >> 6, d = gcol & 63, tt = d >> 1;
#pragma unroll
        for (int tq = 0; tq < 4; ++tq) {
#pragma unroll
          for (int u = 0; u < 4; ++u) {
            int reg = tq * 4 + u;
            int grow = m0 + wr * 64 + mi * 32 + (u + 8 * tq + 4 * half);
            int s = grow & (S_ - 1), b = grow >> 11;
            float v = acc[mi][ni][reg] + bv;
            float other = __shfl_xor(v, 1);  // partner dim (d^1), lane^1
            float cs = cosT[(size_t)(b * S_ + s) * NT2 + tt];
            float sn = sinT[(size_t)(b * S_ + s) * NT2 + tt];
            float vr = (d & 1) ? (other * sn + v * cs) : (v * cs - other * sn);
            if (third == 0) vr *= 0.125f;  // 1/sqrt(D)
            bf16 hv = (bf16)vr;
            bf16 lv = (bf16)(vr - (float)hv);
            size_t idx = (((size_t)(b * H_ + h)) * S_ + s) * D_ + d;
            outH[idx] = hv;
            outL[idx] = lv;
          }
        }
      } else {  // V: bf16, transposed [B,H,D,S]
        const int h = gcol >> 6, d = gcol & 63;
#pragma unroll
        for (int tq = 0; tq < 4; ++tq) {
          int grow = m0 + wr * 64 + mi * 32 + (8 * tq + 4 * half);
          int s = grow & (S_ - 1), b = grow >> 11;
          ushort4 pk;
          unsigned short* pp = (unsigned short*)&pk;
#pragma unroll
          for (int u = 0; u < 4; ++u) {
            float v = acc[mi][ni][tq * 4 + u] + bv;
            bf16 hv = (bf16)v;
            pp[u] = __builtin_bit_cast(unsigned short, hv);
          }
          *(ushort4*)((unsigned short*)VTb +
                      (((size_t)(b * H_ + h)) * D_ + d) * S_ + s) = pk;
        }
      }
    }
}

// ---------------- O-projection GEMM: 64x128, BK=64, zero-conflict layout ---
#define BMo 64
#define BNo 128
#define BKo 64

__global__ __launch_bounds__(256, 4)
void gemm_o_kernel(const bf16* __restrict__ Ah_g, const bf16* __restrict__ Al_g,
                   const bf16* __restrict__ Bh_g, const bf16* __restrict__ Bl_g,
                   const float* __restrict__ bias, float* __restrict__ outF) {
  __shared__ bf16 lA[BMo * 128];  // 16 KB: row = [Ah 64 bf16 | Al 64 bf16]
  __shared__ bf16 lB[BNo * 128];  // 32 KB
  const int tid = threadIdx.x;
  const int n0 = blockIdx.x * BNo, m0 = blockIdx.y * BMo;
  const int wave = tid >> 6, lane = tid & 63;
  const int wr = wave >> 1, wc = wave & 1;  // 2M x 2N wave grid
  const int r = lane & 31, half = lane >> 5;
  const int KD = 1024;
  const int NK = KD / BKo;  // 16

  f32x16 acc[2] = {};   // ni = 0,1
  f32x16 acc2[2] = {};

  for (int kt = 0; kt < NK; ++kt) {
    const int k0 = kt * BKo;
    {
      // A: 64 rows x 16 chunks = 1024; B: 128 x 16 = 2048; 12 per thread
#pragma unroll
      for (int i = 0; i < 12; ++i) {
        int c = i * 256 + tid;
        if (i < 4) {  // A chunks 0..1023
          int row = c >> 4, u = c & 15;
          int us = u ^ (row & 15);
          const bf16* sA = (us < 8) ? Ah_g : Al_g;
          char* lp = (char*)lA + (size_t)c * 16;
          gload_lds16((const char*)(sA + (size_t)(m0 + row) * KD + k0) +
                          (us & 7) * 16,
                      lp);
        } else {  // B chunks 0..2047
          int cb = c - 1024;
          int row = cb >> 4, u = cb & 15;
          int us = u ^ (row & 15);
          const bf16* sB = (us < 8) ? Bh_g : Bl_g;
          char* lp = (char*)lB + (size_t)cb * 16;
          gload_lds16((const char*)(sB + (size_t)(n0 + row) * KD + k0) +
                          (us & 7) * 16,
                      lp);
        }
      }
    }
    __syncthreads();
#pragma unroll
    for (int ks = 0; ks < 4; ++ks) {
      bf16x8 a_h, a_l, b_h[2], b_l[2];
      {
        int row = wr * 32 + r;
        int sw = (row & 15) << 4;
        const char* base = (const char*)lA + row * 256;
        a_h = *(const bf16x8*)(base + ((ks * 32 + half * 16) ^ sw));
        a_l = *(const bf16x8*)(base + ((128 + ks * 32 + half * 16) ^ sw));
      }
#pragma unroll
      for (int ni = 0; ni < 2; ++ni) {
        int row = wc * 64 + ni * 32 + r;
        int sw = (row & 15) << 4;
        const char* base = (const char*)lB + row * 256;
        b_h[ni] = *(const bf16x8*)(base + ((ks * 32 + half * 16) ^ sw));
        b_l[ni] = *(const bf16x8*)(base + ((128 + ks * 32 + half * 16) ^ sw));
      }
#pragma unroll
      for (int ni = 0; ni < 2; ++ni) {
        acc[ni] = MFMA32(a_h, b_h[ni], acc[ni]);
        acc[ni] = MFMA32(a_h, b_l[ni], acc[ni]);
        acc2[ni] = MFMA32(a_l, b_h[ni], acc2[ni]);
      }
    }
    __syncthreads();
  }

#pragma unroll
  for (int ni = 0; ni < 2; ++ni) {
    const int gcol = n0 + wc * 64 + ni * 32 + r;
    const float bv = bias[gcol];
#pragma unroll
    for (int tq = 0; tq < 4; ++tq)
#pragma unroll
      for (int u = 0; u < 4; ++u) {
        int grow = m0 + wr * 32 + (u + 8 * tq + 4 * half);
        outF[(size_t)grow * E_ + gcol] =
            acc[ni][tq * 4 + u] + acc2[ni][tq * 4 + u] + bv;
      }
  }
}

// ---------------- flash attention (in-register softmax, swapped QK^T) -------
__global__ __launch_bounds__(256)
void attn_kernel(const bf16* __restrict__ Qh, const bf16* __restrict__ Ql,
                 const bf16* __restrict__ Kh, const bf16* __restrict__ Kl,
                 const bf16* __restrict__ VT, bf16* __restrict__ Ch,
                 bf16* __restrict__ Cl) {
  __shared__ bf16 sKh[2][KVB * 64];
  __shared__ bf16 sKl[2][KVB * 64];
  __shared__ bf16 sV[2][KVB * 64];  // [d=64][key-pos=64], row-XOR-swizzled

  const int tid = threadIdx.x;
  const int wave = tid >> 6, lane = tid & 63;
  const int r = lane & 15, hq = lane >> 4;
  const int bid = blockIdx.x;
  const int swz = (bid & 7) * 64 + (bid >> 3);  // XCD-chunked (512 % 8 == 0)
  const int bh = swz >> 4, qblk = swz & 15;
  const int q0 = qblk * 128 + wave * 32;
  const size_t hb = (size_t)bh * (S_ * D_);
  const size_t vb = (size_t)bh * (D_ * S_);

  bf16x8 qh[2][2], ql[2][2];
#pragma unroll
  for (int mi = 0; mi < 2; ++mi)
#pragma unroll
    for (int ks = 0; ks < 2; ++ks) {
      size_t off = hb + (size_t)(q0 + mi * 16 + r) * D_ + ks * 32 + hq * 8;
      qh[mi][ks] = *(const bf16x8*)&Qh[off];
      ql[mi][ks] = *(const bf16x8*)&Ql[off];
    }

  float m_lane[2] = {-1e30f, -1e30f};
  float l_lane[2] = {0.f, 0.f};
  f32x4 o[2][4] = {};

  auto stageK = [&](int kt, int buf) {
    const bf16* kbh = Kh + hb + (size_t)kt * (KVB * D_);
    const bf16* kbl = Kl + hb + (size_t)kt * (KVB * D_);
#pragma unroll
    for (int i = 0; i < 2; ++i) {
      int c = i * 256 + tid;
      int ldo = (i * 256 + wave * 64) * 16;
      int cs = c ^ ((c >> 3) & 7);
      gload_lds16(kbh + cs * 8, (char*)&sKh[buf][0] + ldo);
      gload_lds16(kbl + cs * 8, (char*)&sKl[buf][0] + ldo);
    }
  };
  uint4 vld[2];
  auto loadV = [&](int kt) {
    const bf16* vbp = VT + vb + kt * KVB;
#pragma unroll
    for (int i = 0; i < 2; ++i) {
      int c = i * 256 + tid;
      int row = c >> 3, w = c & 7;
      vld[i] = *(const uint4*)(vbp + (size_t)row * S_ + w * 8);
    }
  };
  auto writeV = [&](int buf) {
#pragma unroll
    for (int i = 0; i < 2; ++i) {
      int c = i * 256 + tid;
      int row = c >> 3, w = c & 7;
      int pb0 = (w >> 2) * 32 + (w & 1) * 16 + ((w >> 1) & 1) * 4;
      char* base = (char*)&sV[buf][0] + row * 128;
      uint2 lo = {vld[i].x, vld[i].y};
      uint2 hi = {vld[i].z, vld[i].w};
      *(uint2*)(base + ((pb0 * 2) ^ ((row & 7) << 4))) = lo;
      *(uint2*)(base + (((pb0 + 8) * 2) ^ ((row & 7) << 4))) = hi;
    }
  };

  stageK(0, 0);
  loadV(0);
  writeV(0);
  __syncthreads();
  int cur = 0;

  for (int kt = 0; kt < S_ / KVB; ++kt) {
    if (kt + 1 < S_ / KVB) {
      stageK(kt + 1, cur ^ 1);
      loadV(kt + 1);
    }

    // ---- QK^T (swapped: A=K, B=Q) ----
    f32x4 sf[2][4] = {};
#pragma unroll
    for (int nf = 0; nf < 4; ++nf)
#pragma unroll
      for (int ks = 0; ks < 2; ++ks) {
        int kk = nf * 16 + r;
        int boff = (kk * 128 + ks * 64 + hq * 16) ^ ((kk & 7) << 4);
        bf16x8 kkh = *(const bf16x8*)((const char*)&sKh[cur][0] + boff);
        bf16x8 kkl = *(const bf16x8*)((const char*)&sKl[cur][0] + boff);
#pragma unroll
        for (int mi = 0; mi < 2; ++mi) {
          sf[mi][nf] = MFMA16(kkh, qh[mi][ks], sf[mi][nf]);
          sf[mi][nf] = MFMA16(kkh, ql[mi][ks], sf[mi][nf]);
          sf[mi][nf] = MFMA16(kkl, qh[mi][ks], sf[mi][nf]);
        }
      }

    // ---- defer-max online softmax (lane-local fast path) ----
    float lmax[2];
#pragma unroll
    for (int mi = 0; mi < 2; ++mi) {
      f32x4 m4;
#pragma unroll
      for (int e = 0; e < 4; ++e)
        m4[e] = fmaxf(fmaxf(sf[mi][0][e], sf[mi][1][e]),
                      fmaxf(sf[mi][2][e], sf[mi][3][e]));
      lmax[mi] = fmaxf(fmaxf(m4[0], m4[1]), fmaxf(m4[2], m4[3]));
    }
    int need = (lmax[0] > m_lane[0] + 8.f) || (lmax[1] > m_lane[1] + 8.f);
    if (__any(need)) {
#pragma unroll
      for (int mi = 0; mi < 2; ++mi) {
        float mx = lmax[mi];
        mx = fmaxf(mx, __shfl_xor(mx, 16));
        mx = fmaxf(mx, __shfl_xor(mx, 32));
        float mn = fmaxf(m_lane[mi], mx);
        float al = __expf(m_lane[mi] - mn);
        l_lane[mi] *= al;
        m_lane[mi] = mn;
        int alb = __builtin_bit_cast(int, al);
#pragma unroll
        for (int j = 0; j < 4; ++j) {
          int g = __builtin_amdgcn_ds_bpermute((hq * 4 + j) * 4, alb);
          float a = __builtin_bit_cast(float, g);
#pragma unroll
          for (int nd = 0; nd < 4; ++nd) o[mi][nd][j] *= a;
        }
      }
    }
    bf16x8 pa[2][2];
#pragma unroll
    for (int mi = 0; mi < 2; ++mi) {
      f32x4 s4 = {};
#pragma unroll
      for (int nf = 0; nf < 4; ++nf)
#pragma unroll
        for (int e = 0; e < 4; ++e) {
          float pv = __expf(sf[mi][nf][e] - m_lane[mi]);
          sf[mi][nf][e] = pv;
          s4[e] += pv;
        }
      l_lane[mi] += s4[0] + s4[1] + s4[2] + s4[3];
#pragma unroll
      for (int ks = 0; ks < 2; ++ks) {
        bf16x8 t;
#pragma unroll
        for (int e = 0; e < 4; ++e) {
          t[e] = (bf16)sf[mi][2 * ks][e];
          t[4 + e] = (bf16)sf[mi][2 * ks + 1][e];
        }
        pa[mi][ks] = t;
      }
    }

    // ---- PV ----
#pragma unroll
    for (int nd = 0; nd < 4; ++nd)
#pragma unroll
      for (int ks = 0; ks < 2; ++ks) {
        int dd = nd * 16 + r;
        int boff = (dd * 128 + ks * 64 + hq * 16) ^ ((dd & 7) << 4);
        bf16x8 vv = *(const bf16x8*)((const char*)&sV[cur][0] + boff);
#pragma unroll
        for (int mi = 0; mi < 2; ++mi)
          o[mi][nd] = MFMA16(pa[mi][ks], vv, o[mi][nd]);
      }

    if (kt + 1 < S_ / KVB) writeV(cur ^ 1);
    __syncthreads();
    cur ^= 1;
  }

  // ---- epilogue ----
  const int b = bh >> 4, h = bh & 15;
  float lq[2][4];
#pragma unroll
  for (int mi = 0; mi < 2; ++mi) {
    float lr = l_lane[mi];
    lr += __shfl_xor(lr, 16);
    lr += __shfl_xor(lr, 32);
    int lb = __builtin_bit_cast(int, lr);
#pragma unroll
    for (int j = 0; j < 4; ++j) {
      int g = __builtin_amdgcn_ds_bpermute((hq * 4 + j) * 4, lb);
      lq[mi][j] = __builtin_bit_cast(float, g);
    }
  }
#pragma unroll
  for (int mi = 0; mi < 2; ++mi)
#pragma unroll
    for (int nd = 0; nd < 4; ++nd)
#pragma unroll
      for (int j = 0; j < 4; ++j) {
        int s = q0 + mi * 16 + hq * 4 + j;
        int d = nd * 16 + r;
        float ov = o[mi][nd][j] / lq[mi][j];
        bf16 hv = (bf16)ov;
        bf16 lv = (bf16)(ov - (float)hv);
        size_t idx = (((size_t)(b * S_ + s)) * H_ + h) * D_ + d;
        Ch[idx] = hv;
        Cl[idx] = lv;
      }
}

// ---------------- host ----------------
extern "C" void kernel_launch(void* const* d_in, const int* in_sizes, int n_in,
                              void* d_out, int out_size, void* d_ws, size_t ws_size,
                              hipStream_t stream) {
  const float* x = (const float*)d_in[0];
  const int* pos = (const int*)d_in[1];
  const float* Wq = (const float*)d_in[2];
  const float* bq = (const float*)d_in[3];
  const float* Wk = (const float*)d_in[4];
  const float* bk = (const float*)d_in[5];
  const float* Wv = (const float*)d_in[6];
  const float* bv = (const float*)d_in[7];
  const float* Wo = (const float*)d_in[8];
  const float* bo = (const float*)d_in[9];
  float* out = (float*)d_out;

  char* p = (char*)d_ws;
  auto alloc = [&](size_t bytes) {
    char* rp = p;
    p += (bytes + 255) & ~(size_t)255;
    return rp;
  };
  const size_t XB = (size_t)M_ * E_ * sizeof(bf16);        // 8 MiB
  const size_t WB = (size_t)E_ * E_ * sizeof(bf16);        // 2 MiB
  const size_t TB = (size_t)B_ * S_ * NT2 * sizeof(float); // 256 KiB
  bf16* Xh = (bf16*)alloc(XB);
  bf16* Xl = (bf16*)alloc(XB);
  bf16* WqTh = (bf16*)alloc(WB); bf16* WqTl = (bf16*)alloc(WB);
  bf16* WkTh = (bf16*)alloc(WB); bf16* WkTl = (bf16*)alloc(WB);
  bf16* WvTh = (bf16*)alloc(WB); bf16* WvTl = (bf16*)alloc(WB);
  bf16* WoTh = (bf16*)alloc(WB); bf16* WoTl = (bf16*)alloc(WB);
  float* cosT = (float*)alloc(TB);
  float* sinT = (float*)alloc(TB);
  bf16* Qh = (bf16*)alloc(XB); bf16* Qlo = (bf16*)alloc(XB);
  bf16* Kh = (bf16*)alloc(XB); bf16* Klo = (bf16*)alloc(XB);
  bf16* VTb = (bf16*)alloc(XB);
  // ctx aliases X (X is dead after the QKV GEMM; attn runs after on same stream)
  bf16* Ch = Xh;
  bf16* Cl = Xl;

  prep_kernel<<<8704, 256, 0, stream>>>(x, pos, Wq, Wk, Wv, Wo, Xh, Xl, WqTh,
                                        WqTl, WkTh, WkTl, WvTh, WvTl, WoTh,
                                        WoTl, cosT, sinT);

  dim3 gq(24, 32);
  gemm_qkv_kernel<<<gq, 256, 0, stream>>>(Xh, Xl, WqTh, WqTl, WkTh, WkTl, WvTh,
                                          WvTl, bq, bk, bv, cosT, sinT, Qh, Qlo,
                                          Kh, Klo, VTb);

  attn_kernel<<<B_ * H_ * (S_ / 128), 256, 0, stream>>>(Qh, Qlo, Kh, Klo, VTb,
                                                        Ch, Cl);

  dim3 go(8, 64);
  gemm_o_kernel<<<go, 256, 0, stream>>>(Ch, Cl, WoTh, WoTl, bo, out);
}

// Round 18
// 203.318 us; speedup vs baseline: 1.0533x; 1.0533x over previous
//
#include <hip/hip_runtime.h>
#include <hip/hip_bf16.h>
#include <math.h>

#define B_ 2
#define S_ 2048
#define E_ 1024
#define H_ 16
#define D_ 64
#define M_ 4096   // B_*S_
#define NT2 32    // D_/2
#define KVB 64

typedef __bf16 bf16;
typedef __bf16 bf16x4 __attribute__((ext_vector_type(4)));
typedef __bf16 bf16x8 __attribute__((ext_vector_type(8)));
typedef float f32x4 __attribute__((ext_vector_type(4)));
typedef float f32x16 __attribute__((ext_vector_type(16)));

__device__ __forceinline__ void gload_lds16(const void* g, void* lds) {
  __builtin_amdgcn_global_load_lds(
      (const __attribute__((address_space(1))) unsigned int*)g,
      (__attribute__((address_space(3))) unsigned int*)lds, 16, 0, 0);
}

#define MFMA16(a, b, c) __builtin_amdgcn_mfma_f32_16x16x32_bf16(a, b, c, 0, 0, 0)
#define MFMA32(a, b, c) __builtin_amdgcn_mfma_f32_32x32x16_bf16(a, b, c, 0, 0, 0)

// ---------------- fused prep: split X + transpose/split 4 W + rope table ----
__global__ __launch_bounds__(256)
void prep_kernel(const float* __restrict__ x, const int* __restrict__ pos,
                 const float* __restrict__ Wq, const float* __restrict__ Wk,
                 const float* __restrict__ Wv, const float* __restrict__ Wo,
                 bf16* __restrict__ Xh, bf16* __restrict__ Xl,
                 bf16* __restrict__ Tqh, bf16* __restrict__ Tql,
                 bf16* __restrict__ Tkh, bf16* __restrict__ Tkl,
                 bf16* __restrict__ Tvh, bf16* __restrict__ Tvl,
                 bf16* __restrict__ Toh, bf16* __restrict__ Tol,
                 float* __restrict__ cosT, float* __restrict__ sinT) {
  const int bid = blockIdx.x;
  if (bid < 4096) {  // ---- split fp32 -> bf16 hi/lo (float4 per thread) ----
    int i = bid * 256 + threadIdx.x;
    float4 v = ((const float4*)x)[i];
    bf16 h0 = (bf16)v.x, h1 = (bf16)v.y, h2 = (bf16)v.z, h3 = (bf16)v.w;
    bf16x4 hv = {h0, h1, h2, h3};
    bf16x4 lv = {(bf16)(v.x - (float)h0), (bf16)(v.y - (float)h1),
                 (bf16)(v.z - (float)h2), (bf16)(v.w - (float)h3)};
    *(bf16x4*)(Xh + 4 * (size_t)i) = hv;
    *(bf16x4*)(Xl + 4 * (size_t)i) = lv;
  } else if (bid < 8192) {  // ---- transpose + split one 32x32 W tile ----
    int t = bid - 4096;
    int z = t >> 10, rem = t & 1023;
    int bx = rem & 31, by = rem >> 5;
    const float* W = z == 0 ? Wq : z == 1 ? Wk : z == 2 ? Wv : Wo;
    bf16* Th = z == 0 ? Tqh : z == 1 ? Tkh : z == 2 ? Tvh : Toh;
    bf16* Tl = z == 0 ? Tql : z == 1 ? Tkl : z == 2 ? Tvl : Tol;
    __shared__ float tile[32][33];
    const int tx = threadIdx.x & 31, ty = threadIdx.x >> 5;  // ty 0..7
    const int c0 = bx * 32, r0 = by * 32;
#pragma unroll
    for (int i = 0; i < 4; ++i)
      tile[ty + 8 * i][tx] = W[(size_t)(r0 + ty + 8 * i) * E_ + c0 + tx];
    __syncthreads();
#pragma unroll
    for (int i = 0; i < 4; ++i) {
      int rr = ty + 8 * i;
      float v = tile[tx][rr];  // = W[r0+tx][c0+rr]
      bf16 hv = (bf16)v;
      size_t oidx = (size_t)(c0 + rr) * E_ + r0 + tx;
      Th[oidx] = hv;
      Tl[oidx] = (bf16)(v - (float)hv);
    }
  } else {  // ---- RoPE cos/sin table ----
    int idx = (bid - 8192) * 256 + threadIdx.x;  // B_*S_*NT2
    int t = idx & 31, bs = idx >> 5;
    double th = pow(10000.0, -(double)(2 * t) / 64.0);
    float ang = (float)pos[bs] * (float)th;  // fp32 product (matches ref)
    double a = (double)ang;
    cosT[idx] = (float)cos(a);
    sinT[idx] = (float)sin(a);
  }
}

// ---------------- fused QKV split-bf16 GEMM, 128^2, 8 waves, BK=64 ---------
// Empirical optimum (r15/r16): gload_lds staging, 8 waves 2Mx4N, 2 blocks/CU
// (16 waves/CU), merged 256B row [Ah 64k | Al 64k] (16 slots), swizzle
// slot ^= row&15 both-sides -> ZERO bank conflicts; 16 K-iterations.
// Perturbations all measured neutral/negative: bigger tile (r7), 4-wave
// 64x64 (r17), phases (r8/r9), dbuf (r5/r14), reg-staging (r13), counted
// vmcnt (r6), setprio (r8/r15), acc-split (r12).
#define BMg 128
#define BNg 128
#define BKq 64

__global__ __launch_bounds__(512, 4)
void gemm_qkv_kernel(const bf16* __restrict__ Ah_g, const bf16* __restrict__ Al_g,
                     const bf16* __restrict__ BhQ, const bf16* __restrict__ BlQ,
                     const bf16* __restrict__ BhK, const bf16* __restrict__ BlK,
                     const bf16* __restrict__ BhV, const bf16* __restrict__ BlV,
                     const float* __restrict__ bqp, const float* __restrict__ bkp,
                     const float* __restrict__ bvp,
                     const float* __restrict__ cosT, const float* __restrict__ sinT,
                     bf16* __restrict__ Qh, bf16* __restrict__ Qlo,
                     bf16* __restrict__ Kh, bf16* __restrict__ Klo,
                     bf16* __restrict__ VTb) {
  __shared__ bf16 lA[BMg * 128];  // 32 KB: row = [Ah 64 bf16 | Al 64 bf16]
  __shared__ bf16 lB[BNg * 128];  // 32 KB
  const int tid = threadIdx.x;        // 0..511
  const int nb = blockIdx.x;          // 0..23
  const int third = nb >> 3;          // 0=Q 1=K 2=V
  const int n0 = (nb & 7) * BNg;
  const int m0 = blockIdx.y * BMg;
  const bf16* Bh_g = third == 0 ? BhQ : third == 1 ? BhK : BhV;
  const bf16* Bl_g = third == 0 ? BlQ : third == 1 ? BlK : BlV;
  const float* bias = third == 0 ? bqp : third == 1 ? bkp : bvp;
  const int wave = tid >> 6, lane = tid & 63;
  const int wr = wave >> 2, wc = wave & 3;  // 2M x 4N wave grid
  const int r = lane & 31, half = lane >> 5;
  const int KD = 1024;
  const int NK = KD / BKq;  // 16

  f32x16 acc[2] = {};   // a_h*b_h and a_h*b_l terms
  f32x16 acc2[2] = {};  // a_l*b_h term (independent chain)

  for (int kt = 0; kt < NK; ++kt) {
    const int k0 = kt * BKq;
    {
#pragma unroll
      for (int i = 0; i < 4; ++i) {
        int c = i * 512 + tid;          // 16B chunk 0..2047
        int row = c >> 4, u = c & 15;
        int us = u ^ (row & 15);        // pre-swizzled source slot
        int uu = us & 7;
        char* lpA = (char*)lA + (size_t)(i * 512 + wave * 64) * 16;
        char* lpB = (char*)lB + (size_t)(i * 512 + wave * 64) * 16;
        const bf16* sA = (us < 8) ? Ah_g : Al_g;
        const bf16* sB = (us < 8) ? Bh_g : Bl_g;
        gload_lds16((const char*)(sA + (size_t)(m0 + row) * KD + k0) + uu * 16,
                    lpA);
        gload_lds16((const char*)(sB + (size_t)(n0 + row) * KD + k0) + uu * 16,
                    lpB);
      }
    }
    __syncthreads();
#pragma unroll
    for (int ks = 0; ks < 4; ++ks) {
      bf16x8 a_h[2], a_l[2], b_h, b_l;
#pragma unroll
      for (int mi = 0; mi < 2; ++mi) {
        int row = wr * 64 + mi * 32 + r;
        int sw = (row & 15) << 4;
        const char* base = (const char*)lA + row * 256;
        a_h[mi] = *(const bf16x8*)(base + ((ks * 32 + half * 16) ^ sw));
        a_l[mi] = *(const bf16x8*)(base + ((128 + ks * 32 + half * 16) ^ sw));
      }
      {
        int row = wc * 32 + r;
        int sw = (row & 15) << 4;
        const char* base = (const char*)lB + row * 256;
        b_h = *(const bf16x8*)(base + ((ks * 32 + half * 16) ^ sw));
        b_l = *(const bf16x8*)(base + ((128 + ks * 32 + half * 16) ^ sw));
      }
#pragma unroll
      for (int mi = 0; mi < 2; ++mi) {
        acc[mi] = MFMA32(a_h[mi], b_h, acc[mi]);
        acc[mi] = MFMA32(a_h[mi], b_l, acc[mi]);
        acc2[mi] = MFMA32(a_l[mi], b_h, acc2[mi]);
      }
    }
    __syncthreads();
  }

  // ---- epilogue ----
#pragma unroll
  for (int mi = 0; mi < 2; ++mi) {
    const int gcol = n0 + wc * 32 + r;
    const float bv = bias[gcol];
    if (third < 2) {  // Q or K: RoPE (+scale for Q), split
      bf16* outH = third == 0 ? Qh : Kh;
      bf16* outL = third == 0 ? Qlo : Klo;
      const int h = gcol >> 6, d = gcol & 63, tt = d >> 1;
#pragma unroll
      for (int tq = 0; tq < 4; ++tq) {
#pragma unroll
        for (int u = 0; u < 4; ++u) {
          int reg = tq * 4 + u;
          int grow = m0 + wr * 64 + mi * 32 + (u + 8 * tq + 4 * half);
          int s = grow & (S_ - 1), b = grow >> 11;
          float v = acc[mi][reg] + acc2[mi][reg] + bv;
          float other = __shfl_xor(v, 1);  // partner dim (d^1), lane^1
          float cs = cosT[(size_t)(b * S_ + s) * NT2 + tt];
          float sn = sinT[(size_t)(b * S_ + s) * NT2 + tt];
          float vr = (d & 1) ? (other * sn + v * cs) : (v * cs - other * sn);
          if (third == 0) vr *= 0.125f;  // 1/sqrt(D)
          bf16 hv = (bf16)vr;
          bf16 lv = (bf16)(vr - (float)hv);
          size_t idx = (((size_t)(b * H_ + h)) * S_ + s) * D_ + d;
          outH[idx] = hv;
          outL[idx] = lv;
        }
      }
    } else {  // V: bf16, transposed [B,H,D,S]
      const int h = gcol >> 6, d = gcol & 63;
#pragma unroll
      for (int tq = 0; tq < 4; ++tq) {
        int grow = m0 + wr * 64 + mi * 32 + (8 * tq + 4 * half);
        int s = grow & (S_ - 1), b = grow >> 11;
        ushort4 pk;
        unsigned short* pp = (unsigned short*)&pk;
#pragma unroll
        for (int u = 0; u < 4; ++u) {
          float v = acc[mi][tq * 4 + u] + acc2[mi][tq * 4 + u] + bv;
          bf16 hv = (bf16)v;
          pp[u] = __builtin_bit_cast(unsigned short, hv);
        }
        *(ushort4*)((unsigned short*)VTb +
                    (((size_t)(b * H_ + h)) * D_ + d) * S_ + s) = pk;
      }
    }
  }
}

// ---------------- O-projection GEMM: 64x128, BK=64, zero-conflict layout ---
#define BMo 64
#define BNo 128
#define BKo 64

__global__ __launch_bounds__(256, 4)
void gemm_o_kernel(const bf16* __restrict__ Ah_g, const bf16* __restrict__ Al_g,
                   const bf16* __restrict__ Bh_g, const bf16* __restrict__ Bl_g,
                   const float* __restrict__ bias, float* __restrict__ outF) {
  __shared__ bf16 lA[BMo * 128];  // 16 KB: row = [Ah 64 bf16 | Al 64 bf16]
  __shared__ bf16 lB[BNo * 128];  // 32 KB
  const int tid = threadIdx.x;
  const int n0 = blockIdx.x * BNo, m0 = blockIdx.y * BMo;
  const int wave = tid >> 6, lane = tid & 63;
  const int wr = wave >> 1, wc = wave & 1;  // 2M x 2N wave grid
  const int r = lane & 31, half = lane >> 5;
  const int KD = 1024;
  const int NK = KD / BKo;  // 16

  f32x16 acc[2] = {};   // ni = 0,1
  f32x16 acc2[2] = {};

  for (int kt = 0; kt < NK; ++kt) {
    const int k0 = kt * BKo;
    {
      // A: 64 rows x 16 chunks = 1024; B: 128 x 16 = 2048; 12 per thread
#pragma unroll
      for (int i = 0; i < 12; ++i) {
        int c = i * 256 + tid;
        if (i < 4) {  // A chunks 0..1023
          int row = c >> 4, u = c & 15;
          int us = u ^ (row & 15);
          const bf16* sA = (us < 8) ? Ah_g : Al_g;
          char* lp = (char*)lA + (size_t)c * 16;
          gload_lds16((const char*)(sA + (size_t)(m0 + row) * KD + k0) +
                          (us & 7) * 16,
                      lp);
        } else {  // B chunks 0..2047
          int cb = c - 1024;
          int row = cb >> 4, u = cb & 15;
          int us = u ^ (row & 15);
          const bf16* sB = (us < 8) ? Bh_g : Bl_g;
          char* lp = (char*)lB + (size_t)cb * 16;
          gload_lds16((const char*)(sB + (size_t)(n0 + row) * KD + k0) +
                          (us & 7) * 16,
                      lp);
        }
      }
    }
    __syncthreads();
#pragma unroll
    for (int ks = 0; ks < 4; ++ks) {
      bf16x8 a_h, a_l, b_h[2], b_l[2];
      {
        int row = wr * 32 + r;
        int sw = (row & 15) << 4;
        const char* base = (const char*)lA + row * 256;
        a_h = *(const bf16x8*)(base + ((ks * 32 + half * 16) ^ sw));
        a_l = *(const bf16x8*)(base + ((128 + ks * 32 + half * 16) ^ sw));
      }
#pragma unroll
      for (int ni = 0; ni < 2; ++ni) {
        int row = wc * 64 + ni * 32 + r;
        int sw = (row & 15) << 4;
        const char* base = (const char*)lB + row * 256;
        b_h[ni] = *(const bf16x8*)(base + ((ks * 32 + half * 16) ^ sw));
        b_l[ni] = *(const bf16x8*)(base + ((128 + ks * 32 + half * 16) ^ sw));
      }
#pragma unroll
      for (int ni = 0; ni < 2; ++ni) {
        acc[ni] = MFMA32(a_h, b_h[ni], acc[ni]);
        acc[ni] = MFMA32(a_h, b_l[ni], acc[ni]);
        acc2[ni] = MFMA32(a_l, b_h[ni], acc2[ni]);
      }
    }
    __syncthreads();
  }

#pragma unroll
  for (int ni = 0; ni < 2; ++ni) {
    const int gcol = n0 + wc * 64 + ni * 32 + r;
    const float bv = bias[gcol];
#pragma unroll
    for (int tq = 0; tq < 4; ++tq)
#pragma unroll
      for (int u = 0; u < 4; ++u) {
        int grow = m0 + wr * 32 + (u + 8 * tq + 4 * half);
        outF[(size_t)grow * E_ + gcol] =
            acc[ni][tq * 4 + u] + acc2[ni][tq * 4 + u] + bv;
      }
  }
}

// ---------------- flash attention (in-register softmax, swapped QK^T) -------
__global__ __launch_bounds__(256)
void attn_kernel(const bf16* __restrict__ Qh, const bf16* __restrict__ Ql,
                 const bf16* __restrict__ Kh, const bf16* __restrict__ Kl,
                 const bf16* __restrict__ VT, bf16* __restrict__ Ch,
                 bf16* __restrict__ Cl) {
  __shared__ bf16 sKh[2][KVB * 64];
  __shared__ bf16 sKl[2][KVB * 64];
  __shared__ bf16 sV[2][KVB * 64];  // [d=64][key-pos=64], row-XOR-swizzled

  const int tid = threadIdx.x;
  const int wave = tid >> 6, lane = tid & 63;
  const int r = lane & 15, hq = lane >> 4;
  const int bid = blockIdx.x;
  const int swz = (bid & 7) * 64 + (bid >> 3);  // XCD-chunked (512 % 8 == 0)
  const int bh = swz >> 4, qblk = swz & 15;
  const int q0 = qblk * 128 + wave * 32;
  const size_t hb = (size_t)bh * (S_ * D_);
  const size_t vb = (size_t)bh * (D_ * S_);

  bf16x8 qh[2][2], ql[2][2];
#pragma unroll
  for (int mi = 0; mi < 2; ++mi)
#pragma unroll
    for (int ks = 0; ks < 2; ++ks) {
      size_t off = hb + (size_t)(q0 + mi * 16 + r) * D_ + ks * 32 + hq * 8;
      qh[mi][ks] = *(const bf16x8*)&Qh[off];
      ql[mi][ks] = *(const bf16x8*)&Ql[off];
    }

  float m_lane[2] = {-1e30f, -1e30f};
  float l_lane[2] = {0.f, 0.f};
  f32x4 o[2][4] = {};

  auto stageK = [&](int kt, int buf) {
    const bf16* kbh = Kh + hb + (size_t)kt * (KVB * D_);
    const bf16* kbl = Kl + hb + (size_t)kt * (KVB * D_);
#pragma unroll
    for (int i = 0; i < 2; ++i) {
      int c = i * 256 + tid;
      int ldo = (i * 256 + wave * 64) * 16;
      int cs = c ^ ((c >> 3) & 7);
      gload_lds16(kbh + cs * 8, (char*)&sKh[buf][0] + ldo);
      gload_lds16(kbl + cs * 8, (char*)&sKl[buf][0] + ldo);
    }
  };
  uint4 vld[2];
  auto loadV = [&](int kt) {
    const bf16* vbp = VT + vb + kt * KVB;
#pragma unroll
    for (int i = 0; i < 2; ++i) {
      int c = i * 256 + tid;
      int row = c >> 3, w = c & 7;
      vld[i] = *(const uint4*)(vbp + (size_t)row * S_ + w * 8);
    }
  };
  auto writeV = [&](int buf) {
#pragma unroll
    for (int i = 0; i < 2; ++i) {
      int c = i * 256 + tid;
      int row = c >> 3, w = c & 7;
      int pb0 = (w >> 2) * 32 + (w & 1) * 16 + ((w >> 1) & 1) * 4;
      char* base = (char*)&sV[buf][0] + row * 128;
      uint2 lo = {vld[i].x, vld[i].y};
      uint2 hi = {vld[i].z, vld[i].w};
      *(uint2*)(base + ((pb0 * 2) ^ ((row & 7) << 4))) = lo;
      *(uint2*)(base + (((pb0 + 8) * 2) ^ ((row & 7) << 4))) = hi;
    }
  };

  stageK(0, 0);
  loadV(0);
  writeV(0);
  __syncthreads();
  int cur = 0;

  for (int kt = 0; kt < S_ / KVB; ++kt) {
    if (kt + 1 < S_ / KVB) {
      stageK(kt + 1, cur ^ 1);
      loadV(kt + 1);
    }

    // ---- QK^T (swapped: A=K, B=Q) ----
    f32x4 sf[2][4] = {};
#pragma unroll
    for (int nf = 0; nf < 4; ++nf)
#pragma unroll
      for (int ks = 0; ks < 2; ++ks) {
        int kk = nf * 16 + r;
        int boff = (kk * 128 + ks * 64 + hq * 16) ^ ((kk & 7) << 4);
        bf16x8 kkh = *(const bf16x8*)((const char*)&sKh[cur][0] + boff);
        bf16x8 kkl = *(const bf16x8*)((const char*)&sKl[cur][0] + boff);
#pragma unroll
        for (int mi = 0; mi < 2; ++mi) {
          sf[mi][nf] = MFMA16(kkh, qh[mi][ks], sf[mi][nf]);
          sf[mi][nf] = MFMA16(kkh, ql[mi][ks], sf[mi][nf]);
          sf[mi][nf] = MFMA16(kkl, qh[mi][ks], sf[mi][nf]);
        }
      }

    // ---- defer-max online softmax (lane-local fast path) ----
    float lmax[2];
#pragma unroll
    for (int mi = 0; mi < 2; ++mi) {
      f32x4 m4;
#pragma unroll
      for (int e = 0; e < 4; ++e)
        m4[e] = fmaxf(fmaxf(sf[mi][0][e], sf[mi][1][e]),
                      fmaxf(sf[mi][2][e], sf[mi][3][e]));
      lmax[mi] = fmaxf(fmaxf(m4[0], m4[1]), fmaxf(m4[2], m4[3]));
    }
    int need = (lmax[0] > m_lane[0] + 8.f) || (lmax[1] > m_lane[1] + 8.f);
    if (__any(need)) {
#pragma unroll
      for (int mi = 0; mi < 2; ++mi) {
        float mx = lmax[mi];
        mx = fmaxf(mx, __shfl_xor(mx, 16));
        mx = fmaxf(mx, __shfl_xor(mx, 32));
        float mn = fmaxf(m_lane[mi], mx);
        float al = __expf(m_lane[mi] - mn);
        l_lane[mi] *= al;
        m_lane[mi] = mn;
        int alb = __builtin_bit_cast(int, al);
#pragma unroll
        for (int j = 0; j < 4; ++j) {
          int g = __builtin_amdgcn_ds_bpermute((hq * 4 + j) * 4, alb);
          float a = __builtin_bit_cast(float, g);
#pragma unroll
          for (int nd = 0; nd < 4; ++nd) o[mi][nd][j] *= a;
        }
      }
    }
    bf16x8 pa[2][2];
#pragma unroll
    for (int mi = 0; mi < 2; ++mi) {
      f32x4 s4 = {};
#pragma unroll
      for (int nf = 0; nf < 4; ++nf)
#pragma unroll
        for (int e = 0; e < 4; ++e) {
          float pv = __expf(sf[mi][nf][e] - m_lane[mi]);
          sf[mi][nf][e] = pv;
          s4[e] += pv;
        }
      l_lane[mi] += s4[0] + s4[1] + s4[2] + s4[3];
#pragma unroll
      for (int ks = 0; ks < 2; ++ks) {
        bf16x8 t;
#pragma unroll
        for (int e = 0; e < 4; ++e) {
          t[e] = (bf16)sf[mi][2 * ks][e];
          t[4 + e] = (bf16)sf[mi][2 * ks + 1][e];
        }
        pa[mi][ks] = t;
      }
    }

    // ---- PV ----
#pragma unroll
    for (int nd = 0; nd < 4; ++nd)
#pragma unroll
      for (int ks = 0; ks < 2; ++ks) {
        int dd = nd * 16 + r;
        int boff = (dd * 128 + ks * 64 + hq * 16) ^ ((dd & 7) << 4);
        bf16x8 vv = *(const bf16x8*)((const char*)&sV[cur][0] + boff);
#pragma unroll
        for (int mi = 0; mi < 2; ++mi)
          o[mi][nd] = MFMA16(pa[mi][ks], vv, o[mi][nd]);
      }

    if (kt + 1 < S_ / KVB) writeV(cur ^ 1);
    __syncthreads();
    cur ^= 1;
  }

  // ---- epilogue ----
  const int b = bh >> 4, h = bh & 15;
  float lq[2][4];
#pragma unroll
  for (int mi = 0; mi < 2; ++mi) {
    float lr = l_lane[mi];
    lr += __shfl_xor(lr, 16);
    lr += __shfl_xor(lr, 32);
    int lb = __builtin_bit_cast(int, lr);
#pragma unroll
    for (int j = 0; j < 4; ++j) {
      int g = __builtin_amdgcn_ds_bpermute((hq * 4 + j) * 4, lb);
      lq[mi][j] = __builtin_bit_cast(float, g);
    }
  }
#pragma unroll
  for (int mi = 0; mi < 2; ++mi)
#pragma unroll
    for (int nd = 0; nd < 4; ++nd)
#pragma unroll
      for (int j = 0; j < 4; ++j) {
        int s = q0 + mi * 16 + hq * 4 + j;
        int d = nd * 16 + r;
        float ov = o[mi][nd][j] / lq[mi][j];
        bf16 hv = (bf16)ov;
        bf16 lv = (bf16)(ov - (float)hv);
        size_t idx = (((size_t)(b * S_ + s)) * H_ + h) * D_ + d;
        Ch[idx] = hv;
        Cl[idx] = lv;
      }
}

// ---------------- host ----------------
extern "C" void kernel_launch(void* const* d_in, const int* in_sizes, int n_in,
                              void* d_out, int out_size, void* d_ws, size_t ws_size,
                              hipStream_t stream) {
  const float* x = (const float*)d_in[0];
  const int* pos = (const int*)d_in[1];
  const float* Wq = (const float*)d_in[2];
  const float* bq = (const float*)d_in[3];
  const float* Wk = (const float*)d_in[4];
  const float* bk = (const float*)d_in[5];
  const float* Wv = (const float*)d_in[6];
  const float* bv = (const float*)d_in[7];
  const float* Wo = (const float*)d_in[8];
  const float* bo = (const float*)d_in[9];
  float* out = (float*)d_out;

  char* p = (char*)d_ws;
  auto alloc = [&](size_t bytes) {
    char* rp = p;
    p += (bytes + 255) & ~(size_t)255;
    return rp;
  };
  const size_t XB = (size_t)M_ * E_ * sizeof(bf16);        // 8 MiB
  const size_t WB = (size_t)E_ * E_ * sizeof(bf16);        // 2 MiB
  const size_t TB = (size_t)B_ * S_ * NT2 * sizeof(float); // 256 KiB
  bf16* Xh = (bf16*)alloc(XB);
  bf16* Xl = (bf16*)alloc(XB);
  bf16* WqTh = (bf16*)alloc(WB); bf16* WqTl = (bf16*)alloc(WB);
  bf16* WkTh = (bf16*)alloc(WB); bf16* WkTl = (bf16*)alloc(WB);
  bf16* WvTh = (bf16*)alloc(WB); bf16* WvTl = (bf16*)alloc(WB);
  bf16* WoTh = (bf16*)alloc(WB); bf16* WoTl = (bf16*)alloc(WB);
  float* cosT = (float*)alloc(TB);
  float* sinT = (float*)alloc(TB);
  bf16* Qh = (bf16*)alloc(XB); bf16* Qlo = (bf16*)alloc(XB);
  bf16* Kh = (bf16*)alloc(XB); bf16* Klo = (bf16*)alloc(XB);
  bf16* VTb = (bf16*)alloc(XB);
  // ctx aliases X (X is dead after the QKV GEMM; attn runs after on same stream)
  bf16* Ch = Xh;
  bf16* Cl = Xl;

  prep_kernel<<<8704, 256, 0, stream>>>(x, pos, Wq, Wk, Wv, Wo, Xh, Xl, WqTh,
                                        WqTl, WkTh, WkTl, WvTh, WvTl, WoTh,
                                        WoTl, cosT, sinT);

  dim3 gq(24, 32);
  gemm_qkv_kernel<<<gq, 512, 0, stream>>>(Xh, Xl, WqTh, WqTl, WkTh, WkTl, WvTh,
                                          WvTl, bq, bk, bv, cosT, sinT, Qh, Qlo,
                                          Kh, Klo, VTb);

  attn_kernel<<<B_ * H_ * (S_ / 128), 256, 0, stream>>>(Qh, Qlo, Kh, Klo, VTb,
                                                        Ch, Cl);

  dim3 go(8, 64);
  gemm_o_kernel<<<go, 256, 0, stream>>>(Ch, Cl, WoTh, WoTl, bo, out);
}

// Round 19
// 202.228 us; speedup vs baseline: 1.0590x; 1.0054x over previous
//
#include <hip/hip_runtime.h>
#include <hip/hip_bf16.h>
#include <math.h>

#define B_ 2
#define S_ 2048
#define E_ 1024
#define H_ 16
#define D_ 64
#define M_ 4096   // B_*S_
#define NT2 32    // D_/2
#define KVB 64

typedef __bf16 bf16;
typedef __bf16 bf16x4 __attribute__((ext_vector_type(4)));
typedef __bf16 bf16x8 __attribute__((ext_vector_type(8)));
typedef float f32x4 __attribute__((ext_vector_type(4)));
typedef float f32x16 __attribute__((ext_vector_type(16)));

__device__ __forceinline__ void gload_lds16(const void* g, void* lds) {
  __builtin_amdgcn_global_load_lds(
      (const __attribute__((address_space(1))) unsigned int*)g,
      (__attribute__((address_space(3))) unsigned int*)lds, 16, 0, 0);
}

#define MFMA16(a, b, c) __builtin_amdgcn_mfma_f32_16x16x32_bf16(a, b, c, 0, 0, 0)
#define MFMA32(a, b, c) __builtin_amdgcn_mfma_f32_32x32x16_bf16(a, b, c, 0, 0, 0)

// ---------------- fused prep: split X + transpose/split 4 W + rope table ----
__global__ __launch_bounds__(256)
void prep_kernel(const float* __restrict__ x, const int* __restrict__ pos,
                 const float* __restrict__ Wq, const float* __restrict__ Wk,
                 const float* __restrict__ Wv, const float* __restrict__ Wo,
                 bf16* __restrict__ Xh, bf16* __restrict__ Xl,
                 bf16* __restrict__ Tqh, bf16* __restrict__ Tql,
                 bf16* __restrict__ Tkh, bf16* __restrict__ Tkl,
                 bf16* __restrict__ Tvh, bf16* __restrict__ Tvl,
                 bf16* __restrict__ Toh, bf16* __restrict__ Tol,
                 float* __restrict__ cosT, float* __restrict__ sinT) {
  const int bid = blockIdx.x;
  if (bid < 4096) {  // ---- split fp32 -> bf16 hi/lo (float4 per thread) ----
    int i = bid * 256 + threadIdx.x;
    float4 v = ((const float4*)x)[i];
    bf16 h0 = (bf16)v.x, h1 = (bf16)v.y, h2 = (bf16)v.z, h3 = (bf16)v.w;
    bf16x4 hv = {h0, h1, h2, h3};
    bf16x4 lv = {(bf16)(v.x - (float)h0), (bf16)(v.y - (float)h1),
                 (bf16)(v.z - (float)h2), (bf16)(v.w - (float)h3)};
    *(bf16x4*)(Xh + 4 * (size_t)i) = hv;
    *(bf16x4*)(Xl + 4 * (size_t)i) = lv;
  } else if (bid < 8192) {  // ---- transpose + split one 32x32 W tile ----
    int t = bid - 4096;
    int z = t >> 10, rem = t & 1023;
    int bx = rem & 31, by = rem >> 5;
    const float* W = z == 0 ? Wq : z == 1 ? Wk : z == 2 ? Wv : Wo;
    bf16* Th = z == 0 ? Tqh : z == 1 ? Tkh : z == 2 ? Tvh : Toh;
    bf16* Tl = z == 0 ? Tql : z == 1 ? Tkl : z == 2 ? Tvl : Tol;
    __shared__ float tile[32][33];
    const int tx = threadIdx.x & 31, ty = threadIdx.x >> 5;  // ty 0..7
    const int c0 = bx * 32, r0 = by * 32;
#pragma unroll
    for (int i = 0; i < 4; ++i)
      tile[ty + 8 * i][tx] = W[(size_t)(r0 + ty + 8 * i) * E_ + c0 + tx];
    __syncthreads();
#pragma unroll
    for (int i = 0; i < 4; ++i) {
      int rr = ty + 8 * i;
      float v = tile[tx][rr];  // = W[r0+tx][c0+rr]
      bf16 hv = (bf16)v;
      size_t oidx = (size_t)(c0 + rr) * E_ + r0 + tx;
      Th[oidx] = hv;
      Tl[oidx] = (bf16)(v - (float)hv);
    }
  } else {  // ---- RoPE cos/sin table ----
    int idx = (bid - 8192) * 256 + threadIdx.x;  // B_*S_*NT2
    int t = idx & 31, bs = idx >> 5;
    double th = pow(10000.0, -(double)(2 * t) / 64.0);
    float ang = (float)pos[bs] * (float)th;  // fp32 product (matches ref)
    double a = (double)ang;
    cosT[idx] = (float)cos(a);
    sinT[idx] = (float)sin(a);
  }
}

// ---------------- fused QKV split-bf16 GEMM, 128^2, 8 waves, BK=64 ---------
// Empirical optimum (r15/r16): gload_lds staging, 8 waves 2Mx4N, 2 blocks/CU
// (16 waves/CU), merged 256B row [Ah 64k | Al 64k] (16 slots), swizzle
// slot ^= row&15 both-sides -> ZERO bank conflicts; 16 K-iterations.
#define BMg 128
#define BNg 128
#define BKq 64

__global__ __launch_bounds__(512, 4)
void gemm_qkv_kernel(const bf16* __restrict__ Ah_g, const bf16* __restrict__ Al_g,
                     const bf16* __restrict__ BhQ, const bf16* __restrict__ BlQ,
                     const bf16* __restrict__ BhK, const bf16* __restrict__ BlK,
                     const bf16* __restrict__ BhV, const bf16* __restrict__ BlV,
                     const float* __restrict__ bqp, const float* __restrict__ bkp,
                     const float* __restrict__ bvp,
                     const float* __restrict__ cosT, const float* __restrict__ sinT,
                     bf16* __restrict__ Qh, bf16* __restrict__ Qlo,
                     bf16* __restrict__ Kh, bf16* __restrict__ Klo,
                     bf16* __restrict__ VTb) {
  __shared__ bf16 lA[BMg * 128];  // 32 KB: row = [Ah 64 bf16 | Al 64 bf16]
  __shared__ bf16 lB[BNg * 128];  // 32 KB
  const int tid = threadIdx.x;        // 0..511
  const int nb = blockIdx.x;          // 0..23
  const int third = nb >> 3;          // 0=Q 1=K 2=V
  const int n0 = (nb & 7) * BNg;
  const int m0 = blockIdx.y * BMg;
  const bf16* Bh_g = third == 0 ? BhQ : third == 1 ? BhK : BhV;
  const bf16* Bl_g = third == 0 ? BlQ : third == 1 ? BlK : BlV;
  const float* bias = third == 0 ? bqp : third == 1 ? bkp : bvp;
  const int wave = tid >> 6, lane = tid & 63;
  const int wr = wave >> 2, wc = wave & 3;  // 2M x 4N wave grid
  const int r = lane & 31, half = lane >> 5;
  const int KD = 1024;
  const int NK = KD / BKq;  // 16

  f32x16 acc[2] = {};   // a_h*b_h and a_h*b_l terms
  f32x16 acc2[2] = {};  // a_l*b_h term (independent chain)

  for (int kt = 0; kt < NK; ++kt) {
    const int k0 = kt * BKq;
    {
#pragma unroll
      for (int i = 0; i < 4; ++i) {
        int c = i * 512 + tid;          // 16B chunk 0..2047
        int row = c >> 4, u = c & 15;
        int us = u ^ (row & 15);        // pre-swizzled source slot
        int uu = us & 7;
        char* lpA = (char*)lA + (size_t)(i * 512 + wave * 64) * 16;
        char* lpB = (char*)lB + (size_t)(i * 512 + wave * 64) * 16;
        const bf16* sA = (us < 8) ? Ah_g : Al_g;
        const bf16* sB = (us < 8) ? Bh_g : Bl_g;
        gload_lds16((const char*)(sA + (size_t)(m0 + row) * KD + k0) + uu * 16,
                    lpA);
        gload_lds16((const char*)(sB + (size_t)(n0 + row) * KD + k0) + uu * 16,
                    lpB);
      }
    }
    __syncthreads();
#pragma unroll
    for (int ks = 0; ks < 4; ++ks) {
      bf16x8 a_h[2], a_l[2], b_h, b_l;
#pragma unroll
      for (int mi = 0; mi < 2; ++mi) {
        int row = wr * 64 + mi * 32 + r;
        int sw = (row & 15) << 4;
        const char* base = (const char*)lA + row * 256;
        a_h[mi] = *(const bf16x8*)(base + ((ks * 32 + half * 16) ^ sw));
        a_l[mi] = *(const bf16x8*)(base + ((128 + ks * 32 + half * 16) ^ sw));
      }
      {
        int row = wc * 32 + r;
        int sw = (row & 15) << 4;
        const char* base = (const char*)lB + row * 256;
        b_h = *(const bf16x8*)(base + ((ks * 32 + half * 16) ^ sw));
        b_l = *(const bf16x8*)(base + ((128 + ks * 32 + half * 16) ^ sw));
      }
#pragma unroll
      for (int mi = 0; mi < 2; ++mi) {
        acc[mi] = MFMA32(a_h[mi], b_h, acc[mi]);
        acc[mi] = MFMA32(a_h[mi], b_l, acc[mi]);
        acc2[mi] = MFMA32(a_l[mi], b_h, acc2[mi]);
      }
    }
    __syncthreads();
  }

  // ---- epilogue ----
#pragma unroll
  for (int mi = 0; mi < 2; ++mi) {
    const int gcol = n0 + wc * 32 + r;
    const float bv = bias[gcol];
    if (third < 2) {  // Q or K: RoPE (+scale for Q), split
      bf16* outH = third == 0 ? Qh : Kh;
      bf16* outL = third == 0 ? Qlo : Klo;
      const int h = gcol >> 6, d = gcol & 63, tt = d >> 1;
#pragma unroll
      for (int tq = 0; tq < 4; ++tq) {
#pragma unroll
        for (int u = 0; u < 4; ++u) {
          int reg = tq * 4 + u;
          int grow = m0 + wr * 64 + mi * 32 + (u + 8 * tq + 4 * half);
          int s = grow & (S_ - 1), b = grow >> 11;
          float v = acc[mi][reg] + acc2[mi][reg] + bv;
          float other = __shfl_xor(v, 1);  // partner dim (d^1), lane^1
          float cs = cosT[(size_t)(b * S_ + s) * NT2 + tt];
          float sn = sinT[(size_t)(b * S_ + s) * NT2 + tt];
          float vr = (d & 1) ? (other * sn + v * cs) : (v * cs - other * sn);
          if (third == 0) vr *= 0.125f;  // 1/sqrt(D)
          bf16 hv = (bf16)vr;
          bf16 lv = (bf16)(vr - (float)hv);
          size_t idx = (((size_t)(b * H_ + h)) * S_ + s) * D_ + d;
          outH[idx] = hv;
          outL[idx] = lv;
        }
      }
    } else {  // V: bf16, transposed [B,H,D,S]
      const int h = gcol >> 6, d = gcol & 63;
#pragma unroll
      for (int tq = 0; tq < 4; ++tq) {
        int grow = m0 + wr * 64 + mi * 32 + (8 * tq + 4 * half);
        int s = grow & (S_ - 1), b = grow >> 11;
        ushort4 pk;
        unsigned short* pp = (unsigned short*)&pk;
#pragma unroll
        for (int u = 0; u < 4; ++u) {
          float v = acc[mi][tq * 4 + u] + acc2[mi][tq * 4 + u] + bv;
          bf16 hv = (bf16)v;
          pp[u] = __builtin_bit_cast(unsigned short, hv);
        }
        *(ushort4*)((unsigned short*)VTb +
                    (((size_t)(b * H_ + h)) * D_ + d) * S_ + s) = pk;
      }
    }
  }
}

// ---------------- O-projection GEMM: 64x128, BK=64, zero-conflict layout ---
#define BMo 64
#define BNo 128
#define BKo 64

__global__ __launch_bounds__(256, 4)
void gemm_o_kernel(const bf16* __restrict__ Ah_g, const bf16* __restrict__ Al_g,
                   const bf16* __restrict__ Bh_g, const bf16* __restrict__ Bl_g,
                   const float* __restrict__ bias, float* __restrict__ outF) {
  __shared__ bf16 lA[BMo * 128];  // 16 KB: row = [Ah 64 bf16 | Al 64 bf16]
  __shared__ bf16 lB[BNo * 128];  // 32 KB
  const int tid = threadIdx.x;
  const int n0 = blockIdx.x * BNo, m0 = blockIdx.y * BMo;
  const int wave = tid >> 6, lane = tid & 63;
  const int wr = wave >> 1, wc = wave & 1;  // 2M x 2N wave grid
  const int r = lane & 31, half = lane >> 5;
  const int KD = 1024;
  const int NK = KD / BKo;  // 16

  f32x16 acc[2] = {};   // ni = 0,1
  f32x16 acc2[2] = {};

  for (int kt = 0; kt < NK; ++kt) {
    const int k0 = kt * BKo;
    {
      // A: 64 rows x 16 chunks = 1024; B: 128 x 16 = 2048; 12 per thread
#pragma unroll
      for (int i = 0; i < 12; ++i) {
        int c = i * 256 + tid;
        if (i < 4) {  // A chunks 0..1023
          int row = c >> 4, u = c & 15;
          int us = u ^ (row & 15);
          const bf16* sA = (us < 8) ? Ah_g : Al_g;
          char* lp = (char*)lA + (size_t)c * 16;
          gload_lds16((const char*)(sA + (size_t)(m0 + row) * KD + k0) +
                          (us & 7) * 16,
                      lp);
        } else {  // B chunks 0..2047
          int cb = c - 1024;
          int row = cb >> 4, u = cb & 15;
          int us = u ^ (row & 15);
          const bf16* sB = (us < 8) ? Bh_g : Bl_g;
          char* lp = (char*)lB + (size_t)cb * 16;
          gload_lds16((const char*)(sB + (size_t)(n0 + row) * KD + k0) +
                          (us & 7) * 16,
                      lp);
        }
      }
    }
    __syncthreads();
#pragma unroll
    for (int ks = 0; ks < 4; ++ks) {
      bf16x8 a_h, a_l, b_h[2], b_l[2];
      {
        int row = wr * 32 + r;
        int sw = (row & 15) << 4;
        const char* base = (const char*)lA + row * 256;
        a_h = *(const bf16x8*)(base + ((ks * 32 + half * 16) ^ sw));
        a_l = *(const bf16x8*)(base + ((128 + ks * 32 + half * 16) ^ sw));
      }
#pragma unroll
      for (int ni = 0; ni < 2; ++ni) {
        int row = wc * 64 + ni * 32 + r;
        int sw = (row & 15) << 4;
        const char* base = (const char*)lB + row * 256;
        b_h[ni] = *(const bf16x8*)(base + ((ks * 32 + half * 16) ^ sw));
        b_l[ni] = *(const bf16x8*)(base + ((128 + ks * 32 + half * 16) ^ sw));
      }
#pragma unroll
      for (int ni = 0; ni < 2; ++ni) {
        acc[ni] = MFMA32(a_h, b_h[ni], acc[ni]);
        acc[ni] = MFMA32(a_h, b_l[ni], acc[ni]);
        acc2[ni] = MFMA32(a_l, b_h[ni], acc2[ni]);
      }
    }
    __syncthreads();
  }

#pragma unroll
  for (int ni = 0; ni < 2; ++ni) {
    const int gcol = n0 + wc * 64 + ni * 32 + r;
    const float bv = bias[gcol];
#pragma unroll
    for (int tq = 0; tq < 4; ++tq)
#pragma unroll
      for (int u = 0; u < 4; ++u) {
        int grow = m0 + wr * 32 + (u + 8 * tq + 4 * half);
        outF[(size_t)grow * E_ + gcol] =
            acc[ni][tq * 4 + u] + acc2[ni][tq * 4 + u] + bv;
      }
  }
}

// ---------------- flash attention (in-register softmax, swapped QK^T) -------
// NEW (r19): K tiles use the r15-verified zero-conflict layout — merged
// [64 rows][256B] (row = [Kh 64 | Kl 64], 16 slots), swizzle slot ^= row&15
// both-sides (pre-swizzled source, linear LDS dest, same XOR on read).
// Replaces the 128B-row 8-slot layout that measured 9.4M residual read
// conflicts in the analogous GEMM pattern (r11).  V path unchanged.
__global__ __launch_bounds__(256)
void attn_kernel(const bf16* __restrict__ Qh, const bf16* __restrict__ Ql,
                 const bf16* __restrict__ Kh, const bf16* __restrict__ Kl,
                 const bf16* __restrict__ VT, bf16* __restrict__ Ch,
                 bf16* __restrict__ Cl) {
  __shared__ bf16 sK[2][KVB * 128];  // 16 KB/buf: row = [Kh 64 | Kl 64]
  __shared__ bf16 sV[2][KVB * 64];   // [d=64][key-pos=64], row-XOR-swizzled

  const int tid = threadIdx.x;
  const int wave = tid >> 6, lane = tid & 63;
  const int r = lane & 15, hq = lane >> 4;
  const int bid = blockIdx.x;
  const int swz = (bid & 7) * 64 + (bid >> 3);  // XCD-chunked (512 % 8 == 0)
  const int bh = swz >> 4, qblk = swz & 15;
  const int q0 = qblk * 128 + wave * 32;
  const size_t hb = (size_t)bh * (S_ * D_);
  const size_t vb = (size_t)bh * (D_ * S_);

  bf16x8 qh[2][2], ql[2][2];
#pragma unroll
  for (int mi = 0; mi < 2; ++mi)
#pragma unroll
    for (int ks = 0; ks < 2; ++ks) {
      size_t off = hb + (size_t)(q0 + mi * 16 + r) * D_ + ks * 32 + hq * 8;
      qh[mi][ks] = *(const bf16x8*)&Qh[off];
      ql[mi][ks] = *(const bf16x8*)&Ql[off];
    }

  float m_lane[2] = {-1e30f, -1e30f};
  float l_lane[2] = {0.f, 0.f};
  f32x4 o[2][4] = {};

  // K staging: merged 256B rows, pre-swizzled source slot us = u ^ (row&15)
  auto stageK = [&](int kt, int buf) {
    const bf16* kbh = Kh + hb + (size_t)kt * (KVB * D_);
    const bf16* kbl = Kl + hb + (size_t)kt * (KVB * D_);
#pragma unroll
    for (int i = 0; i < 4; ++i) {
      int c = i * 256 + tid;          // 16B chunk 0..1023
      int row = c >> 4, u = c & 15;
      int us = u ^ (row & 15);
      const bf16* src = (us < 8) ? kbh : kbl;
      gload_lds16(src + (size_t)row * D_ + (us & 7) * 8,
                  (char*)&sK[buf][0] + (size_t)(i * 256 + wave * 64) * 16);
    }
  };
  uint4 vld[2];
  auto loadV = [&](int kt) {
    const bf16* vbp = VT + vb + kt * KVB;
#pragma unroll
    for (int i = 0; i < 2; ++i) {
      int c = i * 256 + tid;
      int row = c >> 3, w = c & 7;
      vld[i] = *(const uint4*)(vbp + (size_t)row * S_ + w * 8);
    }
  };
  auto writeV = [&](int buf) {
#pragma unroll
    for (int i = 0; i < 2; ++i) {
      int c = i * 256 + tid;
      int row = c >> 3, w = c & 7;
      int pb0 = (w >> 2) * 32 + (w & 1) * 16 + ((w >> 1) & 1) * 4;
      char* base = (char*)&sV[buf][0] + row * 128;
      uint2 lo = {vld[i].x, vld[i].y};
      uint2 hi = {vld[i].z, vld[i].w};
      *(uint2*)(base + ((pb0 * 2) ^ ((row & 7) << 4))) = lo;
      *(uint2*)(base + (((pb0 + 8) * 2) ^ ((row & 7) << 4))) = hi;
    }
  };

  stageK(0, 0);
  loadV(0);
  writeV(0);
  __syncthreads();
  int cur = 0;

  for (int kt = 0; kt < S_ / KVB; ++kt) {
    if (kt + 1 < S_ / KVB) {
      stageK(kt + 1, cur ^ 1);
      loadV(kt + 1);
    }

    // ---- QK^T (swapped: A=K, B=Q); K frags from merged zero-conflict rows
    f32x4 sf[2][4] = {};
#pragma unroll
    for (int nf = 0; nf < 4; ++nf)
#pragma unroll
      for (int ks = 0; ks < 2; ++ks) {
        int kk = nf * 16 + r;
        int sw = (kk & 15) << 4;
        const char* base = (const char*)&sK[cur][0] + kk * 256;
        bf16x8 kkh = *(const bf16x8*)(base + ((ks * 64 + hq * 16) ^ sw));
        bf16x8 kkl = *(const bf16x8*)(base + ((128 + ks * 64 + hq * 16) ^ sw));
#pragma unroll
        for (int mi = 0; mi < 2; ++mi) {
          sf[mi][nf] = MFMA16(kkh, qh[mi][ks], sf[mi][nf]);
          sf[mi][nf] = MFMA16(kkh, ql[mi][ks], sf[mi][nf]);
          sf[mi][nf] = MFMA16(kkl, qh[mi][ks], sf[mi][nf]);
        }
      }

    // ---- defer-max online softmax (lane-local fast path) ----
    float lmax[2];
#pragma unroll
    for (int mi = 0; mi < 2; ++mi) {
      f32x4 m4;
#pragma unroll
      for (int e = 0; e < 4; ++e)
        m4[e] = fmaxf(fmaxf(sf[mi][0][e], sf[mi][1][e]),
                      fmaxf(sf[mi][2][e], sf[mi][3][e]));
      lmax[mi] = fmaxf(fmaxf(m4[0], m4[1]), fmaxf(m4[2], m4[3]));
    }
    int need = (lmax[0] > m_lane[0] + 8.f) || (lmax[1] > m_lane[1] + 8.f);
    if (__any(need)) {
#pragma unroll
      for (int mi = 0; mi < 2; ++mi) {
        float mx = lmax[mi];
        mx = fmaxf(mx, __shfl_xor(mx, 16));
        mx = fmaxf(mx, __shfl_xor(mx, 32));
        float mn = fmaxf(m_lane[mi], mx);
        float al = __expf(m_lane[mi] - mn);
        l_lane[mi] *= al;
        m_lane[mi] = mn;
        int alb = __builtin_bit_cast(int, al);
#pragma unroll
        for (int j = 0; j < 4; ++j) {
          int g = __builtin_amdgcn_ds_bpermute((hq * 4 + j) * 4, alb);
          float a = __builtin_bit_cast(float, g);
#pragma unroll
          for (int nd = 0; nd < 4; ++nd) o[mi][nd][j] *= a;
        }
      }
    }
    bf16x8 pa[2][2];
#pragma unroll
    for (int mi = 0; mi < 2; ++mi) {
      f32x4 s4 = {};
#pragma unroll
      for (int nf = 0; nf < 4; ++nf)
#pragma unroll
        for (int e = 0; e < 4; ++e) {
          float pv = __expf(sf[mi][nf][e] - m_lane[mi]);
          sf[mi][nf][e] = pv;
          s4[e] += pv;
        }
      l_lane[mi] += s4[0] + s4[1] + s4[2] + s4[3];
#pragma unroll
      for (int ks = 0; ks < 2; ++ks) {
        bf16x8 t;
#pragma unroll
        for (int e = 0; e < 4; ++e) {
          t[e] = (bf16)sf[mi][2 * ks][e];
          t[4 + e] = (bf16)sf[mi][2 * ks + 1][e];
        }
        pa[mi][ks] = t;
      }
    }

    // ---- PV ----
#pragma unroll
    for (int nd = 0; nd < 4; ++nd)
#pragma unroll
      for (int ks = 0; ks < 2; ++ks) {
        int dd = nd * 16 + r;
        int boff = (dd * 128 + ks * 64 + hq * 16) ^ ((dd & 7) << 4);
        bf16x8 vv = *(const bf16x8*)((const char*)&sV[cur][0] + boff);
#pragma unroll
        for (int mi = 0; mi < 2; ++mi)
          o[mi][nd] = MFMA16(pa[mi][ks], vv, o[mi][nd]);
      }

    if (kt + 1 < S_ / KVB) writeV(cur ^ 1);
    __syncthreads();
    cur ^= 1;
  }

  // ---- epilogue ----
  const int b = bh >> 4, h = bh & 15;
  float lq[2][4];
#pragma unroll
  for (int mi = 0; mi < 2; ++mi) {
    float lr = l_lane[mi];
    lr += __shfl_xor(lr, 16);
    lr += __shfl_xor(lr, 32);
    int lb = __builtin_bit_cast(int, lr);
#pragma unroll
    for (int j = 0; j < 4; ++j) {
      int g = __builtin_amdgcn_ds_bpermute((hq * 4 + j) * 4, lb);
      lq[mi][j] = __builtin_bit_cast(float, g);
    }
  }
#pragma unroll
  for (int mi = 0; mi < 2; ++mi)
#pragma unroll
    for (int nd = 0; nd < 4; ++nd)
#pragma unroll
      for (int j = 0; j < 4; ++j) {
        int s = q0 + mi * 16 + hq * 4 + j;
        int d = nd * 16 + r;
        float ov = o[mi][nd][j] / lq[mi][j];
        bf16 hv = (bf16)ov;
        bf16 lv = (bf16)(ov - (float)hv);
        size_t idx = (((size_t)(b * S_ + s)) * H_ + h) * D_ + d;
        Ch[idx] = hv;
        Cl[idx] = lv;
      }
}

// ---------------- host ----------------
extern "C" void kernel_launch(void* const* d_in, const int* in_sizes, int n_in,
                              void* d_out, int out_size, void* d_ws, size_t ws_size,
                              hipStream_t stream) {
  const float* x = (const float*)d_in[0];
  const int* pos = (const int*)d_in[1];
  const float* Wq = (const float*)d_in[2];
  const float* bq = (const float*)d_in[3];
  const float* Wk = (const float*)d_in[4];
  const float* bk = (const float*)d_in[5];
  const float* Wv = (const float*)d_in[6];
  const float* bv = (const float*)d_in[7];
  const float* Wo = (const float*)d_in[8];
  const float* bo = (const float*)d_in[9];
  float* out = (float*)d_out;

  char* p = (char*)d_ws;
  auto alloc = [&](size_t bytes) {
    char* rp = p;
    p += (bytes + 255) & ~(size_t)255;
    return rp;
  };
  const size_t XB = (size_t)M_ * E_ * sizeof(bf16);        // 8 MiB
  const size_t WB = (size_t)E_ * E_ * sizeof(bf16);        // 2 MiB
  const size_t TB = (size_t)B_ * S_ * NT2 * sizeof(float); // 256 KiB
  bf16* Xh = (bf16*)alloc(XB);
  bf16* Xl = (bf16*)alloc(XB);
  bf16* WqTh = (bf16*)alloc(WB); bf16* WqTl = (bf16*)alloc(WB);
  bf16* WkTh = (bf16*)alloc(WB); bf16* WkTl = (bf16*)alloc(WB);
  bf16* WvTh = (bf16*)alloc(WB); bf16* WvTl = (bf16*)alloc(WB);
  bf16* WoTh = (bf16*)alloc(WB); bf16* WoTl = (bf16*)alloc(WB);
  float* cosT = (float*)alloc(TB);
  float* sinT = (float*)alloc(TB);
  bf16* Qh = (bf16*)alloc(XB); bf16* Qlo = (bf16*)alloc(XB);
  bf16* Kh = (bf16*)alloc(XB); bf16* Klo = (bf16*)alloc(XB);
  bf16* VTb = (bf16*)alloc(XB);
  // ctx aliases X (X is dead after the QKV GEMM; attn runs after on same stream)
  bf16* Ch = Xh;
  bf16* Cl = Xl;

  prep_kernel<<<8704, 256, 0, stream>>>(x, pos, Wq, Wk, Wv, Wo, Xh, Xl, WqTh,
                                        WqTl, WkTh, WkTl, WvTh, WvTl, WoTh,
                                        WoTl, cosT, sinT);

  dim3 gq(24, 32);
  gemm_qkv_kernel<<<gq, 512, 0, stream>>>(Xh, Xl, WqTh, WqTl, WkTh, WkTl, WvTh,
                                          WvTl, bq, bk, bv, cosT, sinT, Qh, Qlo,
                                          Kh, Klo, VTb);

  attn_kernel<<<B_ * H_ * (S_ / 128), 256, 0, stream>>>(Qh, Qlo, Kh, Klo, VTb,
                                                        Ch, Cl);

  dim3 go(8, 64);
  gemm_o_kernel<<<go, 256, 0, stream>>>(Ch, Cl, WoTh, WoTl, bo, out);
}